// Round 1
// baseline (768.856 us; speedup 1.0000x reference)
//
#include <hip/hip_runtime.h>
#include <hip/hip_bf16.h>
#include <cstdint>
#include <cstddef>

#define HIDDEN 1024
#define NHEADS 16
#define HDIM 64
#define BATCH 2
#define SEQ 2048
#define MROWS (BATCH*SEQ)   // 4096

typedef __attribute__((ext_vector_type(8))) short short8;
typedef __attribute__((ext_vector_type(4))) float float4v;

__device__ __forceinline__ short f2bf(float f) {
    union { float f; uint32_t u; } v; v.f = f;
    uint32_t u = v.u;
    uint32_t r = (u + 0x7fffu + ((u >> 16) & 1u)) >> 16;
    return (short)r;
}

// ---------------- fp32 -> bf16 convert ----------------
__global__ void conv_f32_bf16(const float* __restrict__ src, short* __restrict__ dst, int n8) {
    int i = blockIdx.x * blockDim.x + threadIdx.x;
    if (i < n8) {
        const float4v* s = (const float4v*)src;
        float4v a = s[2 * i], b = s[2 * i + 1];
        short8 o;
        o[0] = f2bf(a[0]); o[1] = f2bf(a[1]); o[2] = f2bf(a[2]); o[3] = f2bf(a[3]);
        o[4] = f2bf(b[0]); o[5] = f2bf(b[1]); o[6] = f2bf(b[2]); o[7] = f2bf(b[3]);
        ((short8*)dst)[i] = o;
    }
}

// ---------------- QKV projection GEMM: Y = X * W^T + b (bf16 out) ----------------
// X: [4096,1024] bf16 row-major; W: [1024,1024] bf16 row-major ([out,in] => B^T layout)
// tile 128x128, BK=64, 4 waves (2x2 of 64x64), 16x16x32 bf16 MFMA
__global__ __launch_bounds__(256, 2) void proj_gemm(
    const short* __restrict__ Xb,
    const short* __restrict__ Wb0, const short* __restrict__ Wb1, const short* __restrict__ Wb2,
    const float* __restrict__ b0, const float* __restrict__ b1, const float* __restrict__ b2,
    short* __restrict__ O0, short* __restrict__ O1, short* __restrict__ O2)
{
    const int z = blockIdx.z;
    const short* W  = (z == 0) ? Wb0 : (z == 1) ? Wb1 : Wb2;
    const float* bias = (z == 0) ? b0 : (z == 1) ? b1 : b2;
    short* Out = (z == 0) ? O0 : (z == 1) ? O1 : O2;

    __shared__ short As[128 * 72];
    __shared__ short Bs[128 * 72];

    const int t = threadIdx.x;
    const int lane = t & 63, w = t >> 6;
    const int wm = w >> 1, wn = w & 1;
    const int quad = lane >> 4, l16 = lane & 15;

    const int m0 = blockIdx.y * 128;
    const int n0 = blockIdx.x * 128;

    float4v acc[4][4];
#pragma unroll
    for (int i = 0; i < 4; i++)
#pragma unroll
        for (int j = 0; j < 4; j++) acc[i][j] = (float4v){0.f, 0.f, 0.f, 0.f};

    for (int k0 = 0; k0 < HIDDEN; k0 += 64) {
        __syncthreads();
#pragma unroll
        for (int j = 0; j < 4; j++) {
            int cid = t + j * 256;
            int row = cid >> 3, c = cid & 7;
            *(short8*)&As[row * 72 + c * 8] = *(const short8*)&Xb[(size_t)(m0 + row) * HIDDEN + k0 + c * 8];
            *(short8*)&Bs[row * 72 + c * 8] = *(const short8*)&W[(size_t)(n0 + row) * HIDDEN + k0 + c * 8];
        }
        __syncthreads();
#pragma unroll
        for (int kj = 0; kj < 2; kj++) {
            short8 a[4], bfr[4];
#pragma unroll
            for (int i = 0; i < 4; i++)
                a[i] = *(const short8*)&As[(wm * 64 + i * 16 + l16) * 72 + kj * 32 + quad * 8];
#pragma unroll
            for (int j = 0; j < 4; j++)
                bfr[j] = *(const short8*)&Bs[(wn * 64 + j * 16 + l16) * 72 + kj * 32 + quad * 8];
#pragma unroll
            for (int i = 0; i < 4; i++)
#pragma unroll
                for (int j = 0; j < 4; j++)
                    acc[i][j] = __builtin_amdgcn_mfma_f32_16x16x32_bf16(a[i], bfr[j], acc[i][j], 0, 0, 0);
        }
    }

#pragma unroll
    for (int i = 0; i < 4; i++)
#pragma unroll
        for (int j = 0; j < 4; j++) {
            int n = n0 + wn * 64 + j * 16 + l16;
            float bv = bias[n];
#pragma unroll
            for (int r = 0; r < 4; r++) {
                int m = m0 + wm * 64 + i * 16 + quad * 4 + r;
                Out[(size_t)m * HIDDEN + n] = f2bf(acc[i][j][r] + bv);
            }
        }
}

// ---------------- fused attention (2-pass flash, writes probs) ----------------
// grid: (S/64, B*NHEADS); block 256 (4 waves). Wave w owns q-rows w*16..w*16+15.
__global__ __launch_bounds__(256, 2) void attn(
    const short* __restrict__ Qb, const short* __restrict__ Kb, const short* __restrict__ Vb,
    float* __restrict__ ctx, float* __restrict__ probs)
{
    const int bh = blockIdx.y;           // b*16 + h
    const int b = bh >> 4, h = bh & 15;
    const int q0 = blockIdx.x * 64;

    __shared__ short Qs[64 * 72];
    __shared__ short Ks[64 * 72];
    __shared__ short Ps[64 * 72];
    __shared__ short Vt[64 * 72];

    const int t = threadIdx.x;
    const int lane = t & 63, w = t >> 6;
    const int quad = lane >> 4, l16 = lane & 15;

    const short* qp = Qb + (size_t)(b * SEQ + q0) * HIDDEN + h * 64;
    const short* kp = Kb + (size_t)(b * SEQ) * HIDDEN + h * 64;
    const short* vp = Vb + (size_t)(b * SEQ) * HIDDEN + h * 64;

    // load Q tile [64 x 64]
#pragma unroll
    for (int j = 0; j < 2; j++) {
        int cid = t + j * 256;
        int row = cid >> 3, c = cid & 7;
        *(short8*)&Qs[row * 72 + c * 8] = *(const short8*)&qp[(size_t)row * HIDDEN + c * 8];
    }

    float m_r[4], l_r[4];
#pragma unroll
    for (int r = 0; r < 4; r++) { m_r[r] = -1e30f; l_r[r] = 0.f; }
    const float scale = 0.125f;  // 1/sqrt(64)

    // ---- pass 1: row max + denominator (stream K, no stores) ----
    for (int kb = 0; kb < SEQ / 64; kb++) {
        __syncthreads();
#pragma unroll
        for (int j = 0; j < 2; j++) {
            int cid = t + j * 256;
            int row = cid >> 3, c = cid & 7;
            *(short8*)&Ks[row * 72 + c * 8] = *(const short8*)&kp[(size_t)(kb * 64 + row) * HIDDEN + c * 8];
        }
        __syncthreads();

        float4v s[4];
#pragma unroll
        for (int ct = 0; ct < 4; ct++) {
            float4v accv = (float4v){0.f, 0.f, 0.f, 0.f};
#pragma unroll
            for (int kj = 0; kj < 2; kj++) {
                short8 a = *(const short8*)&Qs[(w * 16 + l16) * 72 + kj * 32 + quad * 8];
                short8 bf = *(const short8*)&Ks[(ct * 16 + l16) * 72 + kj * 32 + quad * 8];
                accv = __builtin_amdgcn_mfma_f32_16x16x32_bf16(a, bf, accv, 0, 0, 0);
            }
#pragma unroll
            for (int r = 0; r < 4; r++) s[ct][r] = accv[r] * scale;
        }
#pragma unroll
        for (int r = 0; r < 4; r++) {
            float mx = fmaxf(fmaxf(s[0][r], s[1][r]), fmaxf(s[2][r], s[3][r]));
#pragma unroll
            for (int d = 1; d < 16; d <<= 1) mx = fmaxf(mx, __shfl_xor(mx, d, 64));
            float mnew = fmaxf(m_r[r], mx);
            float sum = 0.f;
#pragma unroll
            for (int ct = 0; ct < 4; ct++) sum += __expf(s[ct][r] - mnew);
#pragma unroll
            for (int d = 1; d < 16; d <<= 1) sum += __shfl_xor(sum, d, 64);
            l_r[r] = l_r[r] * __expf(m_r[r] - mnew) + sum;
            m_r[r] = mnew;
        }
    }

    float il[4];
#pragma unroll
    for (int r = 0; r < 4; r++) il[r] = 1.f / l_r[r];

    float4v o[4];
#pragma unroll
    for (int dt = 0; dt < 4; dt++) o[dt] = (float4v){0.f, 0.f, 0.f, 0.f};

    // ---- pass 2: recompute S, write probs, P*V accumulate ----
    for (int kb = 0; kb < SEQ / 64; kb++) {
        __syncthreads();
#pragma unroll
        for (int j = 0; j < 2; j++) {
            int cid = t + j * 256;
            int row = cid >> 3, c = cid & 7;
            *(short8*)&Ks[row * 72 + c * 8] = *(const short8*)&kp[(size_t)(kb * 64 + row) * HIDDEN + c * 8];
            short8 vv = *(const short8*)&vp[(size_t)(kb * 64 + row) * HIDDEN + c * 8];
#pragma unroll
            for (int e = 0; e < 8; e++) Vt[(c * 8 + e) * 72 + row] = vv[e];
        }
        __syncthreads();

#pragma unroll
        for (int ct = 0; ct < 4; ct++) {
            float4v accv = (float4v){0.f, 0.f, 0.f, 0.f};
#pragma unroll
            for (int kj = 0; kj < 2; kj++) {
                short8 a = *(const short8*)&Qs[(w * 16 + l16) * 72 + kj * 32 + quad * 8];
                short8 bf = *(const short8*)&Ks[(ct * 16 + l16) * 72 + kj * 32 + quad * 8];
                accv = __builtin_amdgcn_mfma_f32_16x16x32_bf16(a, bf, accv, 0, 0, 0);
            }
#pragma unroll
            for (int r = 0; r < 4; r++) {
                float p = __expf(accv[r] * scale - m_r[r]) * il[r];
                int grow = q0 + w * 16 + quad * 4 + r;
                int gcol = kb * 64 + ct * 16 + l16;
                probs[((size_t)bh * SEQ + grow) * SEQ + gcol] = p;
                Ps[(w * 16 + quad * 4 + r) * 72 + ct * 16 + l16] = f2bf(p);
            }
        }
        __syncthreads();

#pragma unroll
        for (int dt = 0; dt < 4; dt++) {
#pragma unroll
            for (int kj = 0; kj < 2; kj++) {
                short8 a = *(const short8*)&Ps[(w * 16 + l16) * 72 + kj * 32 + quad * 8];
                short8 bf = *(const short8*)&Vt[(dt * 16 + l16) * 72 + kj * 32 + quad * 8];
                o[dt] = __builtin_amdgcn_mfma_f32_16x16x32_bf16(a, bf, o[dt], 0, 0, 0);
            }
        }
    }

    // ---- write ctx [B,S,1024] ----
#pragma unroll
    for (int dt = 0; dt < 4; dt++) {
#pragma unroll
        for (int r = 0; r < 4; r++) {
            int grow = b * SEQ + q0 + w * 16 + quad * 4 + r;
            int gcol = h * 64 + dt * 16 + l16;
            ctx[(size_t)grow * HIDDEN + gcol] = o[dt][r];
        }
    }
}

extern "C" void kernel_launch(void* const* d_in, const int* in_sizes, int n_in,
                              void* d_out, int out_size, void* d_ws, size_t ws_size,
                              hipStream_t stream) {
    const float* X  = (const float*)d_in[0];
    const float* Wq = (const float*)d_in[1];
    const float* bq = (const float*)d_in[2];
    const float* Wk = (const float*)d_in[3];
    const float* bk = (const float*)d_in[4];
    const float* Wv = (const float*)d_in[5];
    const float* bv = (const float*)d_in[6];

    float* out = (float*)d_out;
    float* ctx = out;                        // [2,2048,1024] = 4194304
    float* probs = out + (size_t)4194304;    // [2,16,2048,2048]

    // workspace layout (bf16 = short)
    char* ws = (char*)d_ws;
    short* Xb  = (short*)(ws);                        // 8 MB
    short* Wqb = (short*)(ws + (8u << 20));           // 2 MB
    short* Wkb = (short*)(ws + (10u << 20));          // 2 MB
    short* Wvb = (short*)(ws + (12u << 20));          // 2 MB
    short* Qb  = (short*)(ws + (14u << 20));          // 8 MB
    short* Kb  = (short*)(ws + (22u << 20));          // 8 MB
    short* Vb  = (short*)(ws + (30u << 20));          // 8 MB

    // 1) convert inputs to bf16
    {
        int n8 = MROWS * HIDDEN / 8;   // 524288
        conv_f32_bf16<<<dim3(n8 / 256), dim3(256), 0, stream>>>(X, Xb, n8);
        int w8 = HIDDEN * HIDDEN / 8;  // 131072
        conv_f32_bf16<<<dim3(w8 / 256), dim3(256), 0, stream>>>(Wq, Wqb, w8);
        conv_f32_bf16<<<dim3(w8 / 256), dim3(256), 0, stream>>>(Wk, Wkb, w8);
        conv_f32_bf16<<<dim3(w8 / 256), dim3(256), 0, stream>>>(Wv, Wvb, w8);
    }

    // 2) q/k/v projections (bf16 out)
    {
        dim3 grid(HIDDEN / 128, MROWS / 128, 3);   // 8 x 32 x 3
        proj_gemm<<<grid, dim3(256), 0, stream>>>(Xb, Wqb, Wkb, Wvb, bq, bk, bv, Qb, Kb, Vb);
    }

    // 3) attention
    {
        dim3 grid(SEQ / 64, BATCH * NHEADS);       // 32 x 32
        attn<<<grid, dim3(256), 0, stream>>>(Qb, Kb, Vb, ctx, probs);
    }
}